// Round 5
// baseline (357.716 us; speedup 1.0000x reference)
//
#include <hip/hip_runtime.h>

#define BATCH 16384
#define LSEQ  50
#define DIN   20
#define CHN   16
#define HID   6

__device__ __forceinline__ float frcp(float x){ return __builtin_amdgcn_rcpf(x); }
__device__ __forceinline__ float fsig(float x){ return frcp(1.0f + __expf(-x)); }
__device__ __forceinline__ float ftanh(float x){ float t = __expf(2.0f*x); return (t - 1.0f) * frcp(t + 1.0f); }
__device__ __forceinline__ float lrelu(float v){ return v > 0.0f ? v : 0.1f*v; }

// ---------------- K1: per-row embed -> xeg[r][16] (flat xe) + gig[r][20] (gi, padded) ----------------
__global__ __launch_bounds__(256) void k_embed(
    const float* __restrict__ x,
    const float* __restrict__ we_w, const float* __restrict__ we_b,
    const float* __restrict__ wih,  const float* __restrict__ bih,
    float* __restrict__ xeg, float* __restrict__ gig)
{
  const size_t r = (size_t)blockIdx.x * 256 + threadIdx.x;   // [0, B*L)
  float xv[DIN];
  const float4* xr = (const float4*)(x + r * DIN);
  #pragma unroll
  for (int q = 0; q < 5; ++q) {
    float4 v = xr[q];
    xv[4*q] = v.x; xv[4*q+1] = v.y; xv[4*q+2] = v.z; xv[4*q+3] = v.w;
  }
  float xe[CHN];
  #pragma unroll
  for (int c = 0; c < CHN; ++c) {
    float a = we_b[c];
    #pragma unroll
    for (int d = 0; d < DIN; ++d) a = fmaf(xv[d], we_w[c * DIN + d], a);
    xe[c] = a;
  }
  float4* xo = (float4*)(xeg + r * CHN);
  xo[0] = make_float4(xe[0],  xe[1],  xe[2],  xe[3]);
  xo[1] = make_float4(xe[4],  xe[5],  xe[6],  xe[7]);
  xo[2] = make_float4(xe[8],  xe[9],  xe[10], xe[11]);
  xo[3] = make_float4(xe[12], xe[13], xe[14], xe[15]);
  float gi[18];
  #pragma unroll
  for (int g = 0; g < 18; ++g) {
    float a = bih[g];
    #pragma unroll
    for (int c = 0; c < CHN; ++c) a = fmaf(xe[c], wih[g * CHN + c], a);
    gi[g] = a;
  }
  float4* go = (float4*)(gig + r * 20);
  go[0] = make_float4(gi[0],  gi[1],  gi[2],  gi[3]);
  go[1] = make_float4(gi[4],  gi[5],  gi[6],  gi[7]);
  go[2] = make_float4(gi[8],  gi[9],  gi[10], gi[11]);
  go[3] = make_float4(gi[12], gi[13], gi[14], gi[15]);
  go[4] = make_float4(gi[16], gi[17], 0.0f, 0.0f);
}

// ---------------- K2: GRU, element-per-lane, LDS-tiled coalesced input, transposed output ----------
// gig: [elem][50][20] row-major. x4g (transposed): [blk][l*6+h][e64].
// LDS sG: [10 l][20 g][65] floats = 52000 B. 1 wave/block, 256 blocks.
__global__ __launch_bounds__(64) void k_gru(
    const float* __restrict__ gig,
    const float* __restrict__ whh, const float* __restrict__ bhh,
    float* __restrict__ x4g)
{
  __shared__ float sG[10 * 20 * 65];
  const int lane = threadIdx.x;
  const int blk  = blockIdx.x;
  const float* gbase = gig + (size_t)blk * 64 * 1000;
  float* obase = x4g + (size_t)blk * 19200 + lane;

  float wh[18][HID];
  #pragma unroll
  for (int g = 0; g < 18; ++g)
    #pragma unroll
    for (int k = 0; k < HID; ++k) wh[g][k] = whh[g * HID + k];
  float bh[18];
  #pragma unroll
  for (int g = 0; g < 18; ++g) bh[g] = bhh[g];

  float hh[HID];
  #pragma unroll
  for (int k = 0; k < HID; ++k) hh[k] = 0.0f;

  const bool act = lane < 50;                 // 50 float4 per element-tile
  float* dst = sG + (4 * lane) * 65;          // (4*lane + j)*65 + e ; j -> +65

  for (int t = 0; t < 5; ++t) {
    const float* tb = gbase + t * 200 + 4 * lane;
    // ---- loader: 64 element-rounds, chunks of 16 (register-pipelined) ----
    #pragma unroll
    for (int ch = 0; ch < 4; ++ch) {
      float4 buf[16];
      #pragma unroll
      for (int i = 0; i < 16; ++i) {
        const int e = ch * 16 + i;
        buf[i] = act ? *(const float4*)(tb + (size_t)e * 1000)
                     : make_float4(0.f, 0.f, 0.f, 0.f);
      }
      #pragma unroll
      for (int i = 0; i < 16; ++i) {
        const int e = ch * 16 + i;
        if (act) {
          dst[e]       = buf[i].x;
          dst[e + 65]  = buf[i].y;
          dst[e + 130] = buf[i].z;
          dst[e + 195] = buf[i].w;
        }
      }
    }
    __syncthreads();
    // ---- 10 GRU steps from LDS ----
    #pragma unroll
    for (int ll = 0; ll < 10; ++ll) {
      const int l = t * 10 + ll;
      const float* gl = sG + ll * 1300 + lane;   // + g*65
      float c[18];
      #pragma unroll
      for (int g = 0; g < 18; ++g) c[g] = gl[g * 65];
      float gh[18];
      #pragma unroll
      for (int g = 0; g < 18; ++g) {
        float a = bh[g];
        #pragma unroll
        for (int k = 0; k < HID; ++k) a = fmaf(wh[g][k], hh[k], a);
        gh[g] = a;
      }
      float r0 = fsig(c[0] + gh[0]),  r1 = fsig(c[1] + gh[1]);
      float r2 = fsig(c[2] + gh[2]),  r3 = fsig(c[3] + gh[3]);
      float r4 = fsig(c[4] + gh[4]),  r5 = fsig(c[5] + gh[5]);
      float z0 = fsig(c[6] + gh[6]),  z1 = fsig(c[7] + gh[7]);
      float z2 = fsig(c[8] + gh[8]),  z3 = fsig(c[9] + gh[9]);
      float z4 = fsig(c[10] + gh[10]), z5 = fsig(c[11] + gh[11]);
      float n0 = ftanh(fmaf(r0, gh[12], c[12]));
      float n1 = ftanh(fmaf(r1, gh[13], c[13]));
      float n2 = ftanh(fmaf(r2, gh[14], c[14]));
      float n3 = ftanh(fmaf(r3, gh[15], c[15]));
      float n4 = ftanh(fmaf(r4, gh[16], c[16]));
      float n5 = ftanh(fmaf(r5, gh[17], c[17]));
      hh[0] = fmaf(z0, hh[0] - n0, n0);
      hh[1] = fmaf(z1, hh[1] - n1, n1);
      hh[2] = fmaf(z2, hh[2] - n2, n2);
      hh[3] = fmaf(z3, hh[3] - n3, n3);
      hh[4] = fmaf(z4, hh[4] - n4, n4);
      hh[5] = fmaf(z5, hh[5] - n5, n5);
      #pragma unroll
      for (int h2 = 0; h2 < HID; ++h2) obase[(l * HID + h2) * 64] = hh[h2];
    }
    __syncthreads();
  }
}

// ---------------- K3: per-element wave (R3-proven) — attn, convs, score-softmax, fc -------------
// Per-wave LDS slab (floats), SLAB3 = 2368 -> 37888 B/block -> 4 blocks/CU.
constexpr int SLAB3 = 2368;

__global__ __launch_bounds__(256, 4) void k_tail(
    const float* __restrict__ xeg, const float* __restrict__ x4g,
    const float* __restrict__ attn_w, const float* __restrict__ attn_b,
    const float* __restrict__ c1w, const float* __restrict__ c1b,
    const float* __restrict__ c2w, const float* __restrict__ c2b,
    const float* __restrict__ c3w, const float* __restrict__ c3b,
    const float* __restrict__ fc3w, const float* __restrict__ fc3b,
    float* __restrict__ out)
{
  __shared__ __align__(16) float smem[4 * SLAB3];
  const int tid  = threadIdx.x;
  const int wave = tid >> 6;
  const int lane = tid & 63;
  const int b    = blockIdx.x * 4 + wave;

  float* S    = smem + wave * SLAB3;
  float* sXE  = S;
  float* sY   = S + 400;
  float* R1   = S + 800;
  float* sX4  = S + 1600;
  float* sX4P = S + 1904;
  float* sFE  = S + 2304;

  // ---- stage xe (200 f4, coalesced) and x4 (transposed strided reads) ----
  {
    const float4* xs = (const float4*)(xeg + (size_t)b * 800);
    float4* xd = (float4*)sXE;
    #pragma unroll
    for (int q = 0; q < 3; ++q) xd[lane + 64 * q] = xs[lane + 64 * q];
    if (lane < 8) xd[lane + 192] = xs[lane + 192];
    const float* xq = x4g + (size_t)(b >> 6) * 19200 + (b & 63);
    #pragma unroll
    for (int r = 0; r < 4; ++r) sX4[lane + 64 * r] = xq[(size_t)(lane + 64 * r) * 64];
    if (lane < 44) sX4[lane + 256] = xq[(size_t)(lane + 256) * 64];
  }
  __syncthreads();
  if (lane < LSEQ) {   // build padded x4 rows
    float2 a = *(float2*)(sX4 + lane * 6);
    float2 c = *(float2*)(sX4 + lane * 6 + 2);
    float2 d = *(float2*)(sX4 + lane * 6 + 4);
    *(float2*)(sX4P + lane * 8)     = a;
    *(float2*)(sX4P + lane * 8 + 2) = c;
    *(float2*)(sX4P + lane * 8 + 4) = d;
  }

  // ---- attn rows ----
  if (lane < LSEQ) {
    float a[CHN];
    #pragma unroll
    for (int cc = 0; cc < CHN; ++cc) a[cc] = sXE[cc * LSEQ + lane];
    float o[CHN];
    #pragma unroll
    for (int c = 0; c < CHN; ++c) {
      float acc = attn_b[c];
      #pragma unroll
      for (int cc = 0; cc < CHN; ++cc) acc = fmaf(a[cc], attn_w[c * CHN + cc], acc);
      o[c] = ftanh(acc);
    }
    float4* ad = (float4*)(R1 + lane * CHN);
    ad[0] = make_float4(o[0],  o[1],  o[2],  o[3]);
    ad[1] = make_float4(o[4],  o[5],  o[6],  o[7]);
    ad[2] = make_float4(o[8],  o[9],  o[10], o[11]);
    ad[3] = make_float4(o[12], o[13], o[14], o[15]);
  }
  __syncthreads();

  // ---- convs fused with attn1 reduction ----
  {
    float* sAT = R1;
    const int o = lane & 15;
    const int seg = lane >> 4;
    const int L0 = (seg < 2) ? seg * 13 : 26 + (seg - 2) * 12;
    const int NL = (seg < 2) ? 13 : 12;
    int mcl[17];
    #pragma unroll
    for (int mm = 0; mm < 17; ++mm) {
      int m = L0 - 2 + mm;
      mcl[mm] = min(max(m, 0), LSEQ - 1);
    }
    float z1[13], z2[13], z3[13];
    #pragma unroll
    for (int u = 0; u < 13; ++u) { z1[u] = 0.0f; z2[u] = 0.0f; z3[u] = 0.0f; }
    for (int i = 0; i < CHN; ++i) {
      const float w1 = c1w[o * CHN + i];
      float w2a[3], w3a[5];
      #pragma unroll
      for (int t = 0; t < 3; ++t) w2a[t] = c2w[(o * CHN + i) * 3 + t];
      #pragma unroll
      for (int t = 0; t < 5; ++t) w3a[t] = c3w[(o * CHN + i) * 5 + t];
      const float* xrow = sXE + i * LSEQ;
      float xv[17];
      #pragma unroll
      for (int mm = 0; mm < 17; ++mm) {
        float v = xrow[mcl[mm]];
        if (mm < 2 || mm >= 14) {
          int m = L0 - 2 + mm;
          v = (m == mcl[mm]) ? v : 0.0f;
        }
        xv[mm] = v;
      }
      #pragma unroll
      for (int u = 0; u < 13; ++u) {
        z1[u] = fmaf(w1, xv[u + 2], z1[u]);
        z2[u] = fmaf(w2a[0], xv[u + 1], z2[u]);
        z2[u] = fmaf(w2a[1], xv[u + 2], z2[u]);
        z2[u] = fmaf(w2a[2], xv[u + 3], z2[u]);
        z3[u] = fmaf(w3a[0], xv[u],     z3[u]);
        z3[u] = fmaf(w3a[1], xv[u + 1], z3[u]);
        z3[u] = fmaf(w3a[2], xv[u + 2], z3[u]);
        z3[u] = fmaf(w3a[3], xv[u + 3], z3[u]);
        z3[u] = fmaf(w3a[4], xv[u + 4], z3[u]);
      }
    }
    const float b1v = c1b[o], b2v = c2b[o], b3v = c3b[o];
    float a1 = 0.0f, a2 = 0.0f, a3 = 0.0f;
    #pragma unroll
    for (int u = 0; u < 13; ++u) {
      if (u < NL) {
        int l = L0 + u;
        float v1 = lrelu(z1[u] + b1v);
        float v2 = lrelu(z2[u] + b2v);
        float v3 = lrelu(z3[u] + b3v);
        int f1 = o * LSEQ + l;
        int f2 = (CHN + o) * LSEQ + l;
        int f3 = (2 * CHN + o) * LSEQ + l;
        a1 += v1 * sAT[(f1 / 48) * CHN + ((f1 % 48) & 15)];
        a2 += v2 * sAT[(f2 / 48) * CHN + ((f2 % 48) & 15)];
        a3 += v3 * sAT[(f3 / 48) * CHN + ((f3 % 48) & 15)];
      }
    }
    a1 += __shfl_xor(a1, 16); a1 += __shfl_xor(a1, 32);
    a2 += __shfl_xor(a2, 16); a2 += __shfl_xor(a2, 32);
    a3 += __shfl_xor(a3, 16); a3 += __shfl_xor(a3, 32);
    if (lane < CHN) { sFE[o] = a1; sFE[CHN + o] = a2; sFE[2 * CHN + o] = a3; }
  }
  __syncthreads();

  // ---- 6a ----
  float* sC = R1;
  if (lane < LSEQ) {
    float colj[HID];
    #pragma unroll
    for (int h = 0; h < HID; ++h) colj[h] = sX4[h * LSEQ + lane];
    *(float4*)(sC + lane * 16)     = make_float4(colj[0], colj[1], colj[2], colj[3]);
    *(float2*)(sC + lane * 16 + 4) = make_float2(colj[4], colj[5]);
    float zs = 0.0f;
    for (int i = 0; i < LSEQ; ++i) {
      const float4 r0 = *(const float4*)(sX4P + i * 8);
      const float2 r1 = *(const float2*)(sX4P + i * 8 + 4);
      float s = r0.x * colj[0];
      s = fmaf(r0.y, colj[1], s); s = fmaf(r0.z, colj[2], s);
      s = fmaf(r0.w, colj[3], s); s = fmaf(r1.x, colj[4], s);
      s = fmaf(r1.y, colj[5], s);
      zs += __expf(s * (1.0f / 6.0f));
    }
    const float zi = frcp(zs);
    const float4 q0 = *(const float4*)(sX4P + lane * 8);
    const float2 q1 = *(const float2*)(sX4P + lane * 8 + 4);
    *(float4*)(sC + lane * 16 + 8)  = make_float4(zi*q0.x, zi*q0.y, zi*q0.z, zi*q0.w);
    *(float2*)(sC + lane * 16 + 12) = make_float2(zi*q1.x, zi*q1.y);
  }
  __syncthreads();

  // ---- 6b ----
  if (lane < LSEQ) {
    float rowi[HID];
    {
      const float4 q0 = *(const float4*)(sX4P + lane * 8);
      const float2 q1 = *(const float2*)(sX4P + lane * 8 + 4);
      rowi[0] = q0.x; rowi[1] = q0.y; rowi[2] = q0.z;
      rowi[3] = q0.w; rowi[4] = q1.x; rowi[5] = q1.y;
    }
    float ya[HID];
    #pragma unroll
    for (int h = 0; h < HID; ++h) ya[h] = 0.0f;
    for (int j = 0; j < LSEQ; ++j) {
      const float4 t0 = *(const float4*)(sC + j * 16);
      const float2 t1 = *(const float2*)(sC + j * 16 + 4);
      float s = rowi[0] * t0.x;
      s = fmaf(rowi[1], t0.y, s); s = fmaf(rowi[2], t0.z, s);
      s = fmaf(rowi[3], t0.w, s); s = fmaf(rowi[4], t1.x, s);
      s = fmaf(rowi[5], t1.y, s);
      const float e = __expf(s * (1.0f / 6.0f));
      const float4 w0 = *(const float4*)(sC + j * 16 + 8);
      const float2 w1 = *(const float2*)(sC + j * 16 + 12);
      ya[0] = fmaf(e, w0.x, ya[0]);
      ya[1] = fmaf(e, w0.y, ya[1]);
      ya[2] = fmaf(e, w0.z, ya[2]);
      ya[3] = fmaf(e, w0.w, ya[3]);
      ya[4] = fmaf(e, w1.x, ya[4]);
      ya[5] = fmaf(e, w1.y, ya[5]);
    }
    *(float2*)(sY + lane * 6)     = make_float2(ya[0], ya[1]);
    *(float2*)(sY + lane * 6 + 2) = make_float2(ya[2], ya[3]);
    *(float2*)(sY + lane * 6 + 4) = make_float2(ya[4], ya[5]);
  }
  __syncthreads();

  if (lane < HID) {
    float s = 0.0f;
    for (int m = 0; m < LSEQ; ++m) s += sY[lane * LSEQ + m];
    sFE[48 + lane] = s;
  }
  __syncthreads();
  if (lane < 2) {
    float acc = fc3b[lane];
    const float* wr = fc3w + lane * 54;
    #pragma unroll
    for (int k = 0; k < 54; ++k) acc = fmaf(wr[k], sFE[k], acc);
    out[(size_t)b * 2 + lane] = acc;
  }
}

// ---------------- Fallback: proven R2 monolith (used if ws_size too small) ----------------
constexpr int SLAB = 2560;
__global__ __launch_bounds__(256, 4) void fused_kernel(
    const float* __restrict__ x,
    const float* __restrict__ we_w, const float* __restrict__ we_b,
    const float* __restrict__ attn_w, const float* __restrict__ attn_b,
    const float* __restrict__ c1w, const float* __restrict__ c1b,
    const float* __restrict__ c2w, const float* __restrict__ c2b,
    const float* __restrict__ c3w, const float* __restrict__ c3b,
    const float* __restrict__ wih, const float* __restrict__ whh,
    const float* __restrict__ bih, const float* __restrict__ bhh,
    const float* __restrict__ fc3w, const float* __restrict__ fc3b,
    float* __restrict__ out)
{
  __shared__ __align__(16) float smem[4 * SLAB];
  const int tid  = threadIdx.x;
  const int wave = tid >> 6;
  const int lane = tid & 63;
  const int b    = blockIdx.x * 4 + wave;
  float* S    = smem + wave * SLAB;
  float* sXE  = S;
  float* sY   = S + 400;
  float* R1   = S + 800;
  float* sX4  = S + 1800;
  float* sX4P = S + 2104;
  float* sFE  = S + 2504;
  const float* xb = x + (size_t)b * (LSEQ * DIN);
  if (lane < LSEQ) {
    float xv[DIN];
    const float4* xr = (const float4*)(xb + lane * DIN);
    #pragma unroll
    for (int q = 0; q < 5; ++q) { float4 v = xr[q]; xv[4*q]=v.x; xv[4*q+1]=v.y; xv[4*q+2]=v.z; xv[4*q+3]=v.w; }
    float xe[CHN];
    #pragma unroll
    for (int c = 0; c < CHN; ++c) {
      float a = we_b[c];
      #pragma unroll
      for (int d = 0; d < DIN; ++d) a = fmaf(xv[d], we_w[c * DIN + d], a);
      xe[c] = a;
    }
    float4* xd = (float4*)(sXE + lane * CHN);
    xd[0] = make_float4(xe[0], xe[1], xe[2], xe[3]);
    xd[1] = make_float4(xe[4], xe[5], xe[6], xe[7]);
    xd[2] = make_float4(xe[8], xe[9], xe[10], xe[11]);
    xd[3] = make_float4(xe[12], xe[13], xe[14], xe[15]);
    float gi[18];
    #pragma unroll
    for (int g = 0; g < 18; ++g) {
      float a = bih[g];
      #pragma unroll
      for (int cc = 0; cc < CHN; ++cc) a = fmaf(xe[cc], wih[g * CHN + cc], a);
      gi[g] = a;
    }
    float4* gd = (float4*)(R1 + lane * 20);
    gd[0] = make_float4(gi[0], gi[1], gi[2], gi[3]);
    gd[1] = make_float4(gi[4], gi[5], gi[6], gi[7]);
    gd[2] = make_float4(gi[8], gi[9], gi[10], gi[11]);
    gd[3] = make_float4(gi[12], gi[13], gi[14], gi[15]);
    *(float2*)(R1 + lane * 20 + 16) = make_float2(gi[16], gi[17]);
  }
  __syncthreads();
  {
    const int g18 = (lane < 18) ? lane : 0;
    float wh[HID];
    #pragma unroll
    for (int k = 0; k < HID; ++k) wh[k] = whh[g18 * HID + k];
    const float bh = bhh[g18];
    const int m6 = lane % 6;
    float hh[HID];
    #pragma unroll
    for (int k = 0; k < HID; ++k) hh[k] = 0.0f;
    float hm = 0.0f;
    for (int l = 0; l < LSEQ; ++l) {
      float gh = bh;
      #pragma unroll
      for (int k = 0; k < HID; ++k) gh = fmaf(wh[k], hh[k], gh);
      float ghr = __shfl(gh, m6);
      float ghz = __shfl(gh, m6 + 6);
      float ghn = __shfl(gh, m6 + 12);
      const float* gl = R1 + l * 20;
      float r  = fsig(gl[m6] + ghr);
      float z  = fsig(gl[m6 + 6] + ghz);
      float n  = ftanh(gl[m6 + 12] + r * ghn);
      float hn = fmaf(z, hm - n, n);
      hm = hn;
      #pragma unroll
      for (int k = 0; k < HID; ++k) hh[k] = __shfl(hn, k);
      if (lane < HID) { sX4[l * HID + lane] = hn; sX4P[l * 8 + lane] = hn; }
    }
  }
  __syncthreads();
  if (lane < LSEQ) {
    float a[CHN];
    #pragma unroll
    for (int cc = 0; cc < CHN; ++cc) a[cc] = sXE[cc * LSEQ + lane];
    float o[CHN];
    #pragma unroll
    for (int c = 0; c < CHN; ++c) {
      float acc = attn_b[c];
      #pragma unroll
      for (int cc = 0; cc < CHN; ++cc) acc = fmaf(a[cc], attn_w[c * CHN + cc], acc);
      o[c] = ftanh(acc);
    }
    float4* ad = (float4*)(R1 + lane * CHN);
    ad[0] = make_float4(o[0], o[1], o[2], o[3]);
    ad[1] = make_float4(o[4], o[5], o[6], o[7]);
    ad[2] = make_float4(o[8], o[9], o[10], o[11]);
    ad[3] = make_float4(o[12], o[13], o[14], o[15]);
  }
  __syncthreads();
  {
    float* sAT = R1;
    const int o = lane & 15;
    const int seg = lane >> 4;
    const int L0 = (seg < 2) ? seg * 13 : 26 + (seg - 2) * 12;
    const int NL = (seg < 2) ? 13 : 12;
    int mcl[17];
    #pragma unroll
    for (int mm = 0; mm < 17; ++mm) { int m = L0 - 2 + mm; mcl[mm] = min(max(m, 0), LSEQ - 1); }
    float z1[13], z2[13], z3[13];
    #pragma unroll
    for (int u = 0; u < 13; ++u) { z1[u] = 0.0f; z2[u] = 0.0f; z3[u] = 0.0f; }
    for (int i = 0; i < CHN; ++i) {
      const float w1 = c1w[o * CHN + i];
      float w2a[3], w3a[5];
      #pragma unroll
      for (int t = 0; t < 3; ++t) w2a[t] = c2w[(o * CHN + i) * 3 + t];
      #pragma unroll
      for (int t = 0; t < 5; ++t) w3a[t] = c3w[(o * CHN + i) * 5 + t];
      const float* xrow = sXE + i * LSEQ;
      float xv[17];
      #pragma unroll
      for (int mm = 0; mm < 17; ++mm) {
        float v = xrow[mcl[mm]];
        if (mm < 2 || mm >= 14) { int m = L0 - 2 + mm; v = (m == mcl[mm]) ? v : 0.0f; }
        xv[mm] = v;
      }
      #pragma unroll
      for (int u = 0; u < 13; ++u) {
        z1[u] = fmaf(w1, xv[u + 2], z1[u]);
        z2[u] = fmaf(w2a[0], xv[u + 1], z2[u]);
        z2[u] = fmaf(w2a[1], xv[u + 2], z2[u]);
        z2[u] = fmaf(w2a[2], xv[u + 3], z2[u]);
        z3[u] = fmaf(w3a[0], xv[u],     z3[u]);
        z3[u] = fmaf(w3a[1], xv[u + 1], z3[u]);
        z3[u] = fmaf(w3a[2], xv[u + 2], z3[u]);
        z3[u] = fmaf(w3a[3], xv[u + 3], z3[u]);
        z3[u] = fmaf(w3a[4], xv[u + 4], z3[u]);
      }
    }
    const float b1v = c1b[o], b2v = c2b[o], b3v = c3b[o];
    float a1 = 0.0f, a2 = 0.0f, a3 = 0.0f;
    #pragma unroll
    for (int u = 0; u < 13; ++u) {
      if (u < NL) {
        int l = L0 + u;
        float v1 = lrelu(z1[u] + b1v);
        float v2 = lrelu(z2[u] + b2v);
        float v3 = lrelu(z3[u] + b3v);
        int f1 = o * LSEQ + l;
        int f2 = (CHN + o) * LSEQ + l;
        int f3 = (2 * CHN + o) * LSEQ + l;
        a1 += v1 * sAT[(f1 / 48) * CHN + ((f1 % 48) & 15)];
        a2 += v2 * sAT[(f2 / 48) * CHN + ((f2 % 48) & 15)];
        a3 += v3 * sAT[(f3 / 48) * CHN + ((f3 % 48) & 15)];
      }
    }
    a1 += __shfl_xor(a1, 16); a1 += __shfl_xor(a1, 32);
    a2 += __shfl_xor(a2, 16); a2 += __shfl_xor(a2, 32);
    a3 += __shfl_xor(a3, 16); a3 += __shfl_xor(a3, 32);
    if (lane < CHN) { sFE[o] = a1; sFE[CHN + o] = a2; sFE[2 * CHN + o] = a3; }
  }
  __syncthreads();
  float* sC = R1;
  if (lane < LSEQ) {
    float colj[HID];
    #pragma unroll
    for (int h = 0; h < HID; ++h) colj[h] = sX4[h * LSEQ + lane];
    *(float4*)(sC + lane * 16)     = make_float4(colj[0], colj[1], colj[2], colj[3]);
    *(float2*)(sC + lane * 16 + 4) = make_float2(colj[4], colj[5]);
    float zs = 0.0f;
    for (int i = 0; i < LSEQ; ++i) {
      const float4 r0 = *(const float4*)(sX4P + i * 8);
      const float2 r1 = *(const float2*)(sX4P + i * 8 + 4);
      float s = r0.x * colj[0];
      s = fmaf(r0.y, colj[1], s); s = fmaf(r0.z, colj[2], s);
      s = fmaf(r0.w, colj[3], s); s = fmaf(r1.x, colj[4], s);
      s = fmaf(r1.y, colj[5], s);
      zs += __expf(s * (1.0f / 6.0f));
    }
    const float zi = frcp(zs);
    const float4 q0 = *(const float4*)(sX4P + lane * 8);
    const float2 q1 = *(const float2*)(sX4P + lane * 8 + 4);
    *(float4*)(sC + lane * 16 + 8)  = make_float4(zi*q0.x, zi*q0.y, zi*q0.z, zi*q0.w);
    *(float2*)(sC + lane * 16 + 12) = make_float2(zi*q1.x, zi*q1.y);
  }
  __syncthreads();
  if (lane < LSEQ) {
    float rowi[HID];
    {
      const float4 q0 = *(const float4*)(sX4P + lane * 8);
      const float2 q1 = *(const float2*)(sX4P + lane * 8 + 4);
      rowi[0] = q0.x; rowi[1] = q0.y; rowi[2] = q0.z;
      rowi[3] = q0.w; rowi[4] = q1.x; rowi[5] = q1.y;
    }
    float ya[HID];
    #pragma unroll
    for (int h = 0; h < HID; ++h) ya[h] = 0.0f;
    for (int j = 0; j < LSEQ; ++j) {
      const float4 t0 = *(const float4*)(sC + j * 16);
      const float2 t1 = *(const float2*)(sC + j * 16 + 4);
      float s = rowi[0] * t0.x;
      s = fmaf(rowi[1], t0.y, s); s = fmaf(rowi[2], t0.z, s);
      s = fmaf(rowi[3], t0.w, s); s = fmaf(rowi[4], t1.x, s);
      s = fmaf(rowi[5], t1.y, s);
      const float e = __expf(s * (1.0f / 6.0f));
      const float4 w0 = *(const float4*)(sC + j * 16 + 8);
      const float2 w1 = *(const float2*)(sC + j * 16 + 12);
      ya[0] = fmaf(e, w0.x, ya[0]);
      ya[1] = fmaf(e, w0.y, ya[1]);
      ya[2] = fmaf(e, w0.z, ya[2]);
      ya[3] = fmaf(e, w0.w, ya[3]);
      ya[4] = fmaf(e, w1.x, ya[4]);
      ya[5] = fmaf(e, w1.y, ya[5]);
    }
    *(float2*)(sY + lane * 6)     = make_float2(ya[0], ya[1]);
    *(float2*)(sY + lane * 6 + 2) = make_float2(ya[2], ya[3]);
    *(float2*)(sY + lane * 6 + 4) = make_float2(ya[4], ya[5]);
  }
  __syncthreads();
  if (lane < HID) {
    float s = 0.0f;
    for (int m = 0; m < LSEQ; ++m) s += sY[lane * LSEQ + m];
    sFE[48 + lane] = s;
  }
  __syncthreads();
  if (lane < 2) {
    float acc = fc3b[lane];
    const float* wr = fc3w + lane * 54;
    #pragma unroll
    for (int k = 0; k < 54; ++k) acc = fmaf(wr[k], sFE[k], acc);
    out[(size_t)b * 2 + lane] = acc;
  }
}

extern "C" void kernel_launch(void* const* d_in, const int* in_sizes, int n_in,
                              void* d_out, int out_size, void* d_ws, size_t ws_size,
                              hipStream_t stream) {
  (void)in_sizes; (void)n_in; (void)out_size;
  const float* x      = (const float*)d_in[0];
  const float* we_w   = (const float*)d_in[1];
  const float* we_b   = (const float*)d_in[2];
  const float* attn_w = (const float*)d_in[3];
  const float* attn_b = (const float*)d_in[4];
  const float* c1w    = (const float*)d_in[5];
  const float* c1b    = (const float*)d_in[6];
  const float* c2w    = (const float*)d_in[7];
  const float* c2b    = (const float*)d_in[8];
  const float* c3w    = (const float*)d_in[9];
  const float* c3b    = (const float*)d_in[10];
  const float* wih    = (const float*)d_in[11];
  const float* whh    = (const float*)d_in[12];
  const float* bih    = (const float*)d_in[13];
  const float* bhh    = (const float*)d_in[14];
  const float* fc3w   = (const float*)d_in[15];
  const float* fc3b   = (const float*)d_in[16];
  float* out = (float*)d_out;

  const size_t xe_elems = (size_t)BATCH * 800;   // 52.4 MB
  const size_t gi_elems = (size_t)BATCH * 1000;  // 65.5 MB
  const size_t x4_elems = (size_t)BATCH * 300;   // 19.7 MB (transposed layout)
  const size_t need = (xe_elems + gi_elems + x4_elems) * sizeof(float);

  if (ws_size >= need) {
    float* xeg = (float*)d_ws;
    float* gig = xeg + xe_elems;
    float* x4g = gig + gi_elems;
    k_embed<<<(BATCH * LSEQ) / 256, 256, 0, stream>>>(x, we_w, we_b, wih, bih, xeg, gig);
    k_gru<<<BATCH / 64, 64, 0, stream>>>(gig, whh, bhh, x4g);
    k_tail<<<BATCH / 4, 256, 0, stream>>>(xeg, x4g, attn_w, attn_b,
                                          c1w, c1b, c2w, c2b, c3w, c3b,
                                          fc3w, fc3b, out);
  } else {
    fused_kernel<<<BATCH / 4, 256, 0, stream>>>(
        x, we_w, we_b, attn_w, attn_b, c1w, c1b, c2w, c2b, c3w, c3b,
        wih, whh, bih, bhh, fc3w, fc3b, out);
  }
}

// Round 6
// 294.469 us; speedup vs baseline: 1.2148x; 1.2148x over previous
//
#include <hip/hip_runtime.h>

#define BATCH 16384
#define LSEQ  50
#define DIN   20
#define CHN   16
#define HID   6

__device__ __forceinline__ float frcp(float x){ return __builtin_amdgcn_rcpf(x); }
__device__ __forceinline__ float fsig(float x){ return frcp(1.0f + __expf(-x)); }
__device__ __forceinline__ float ftanh(float x){ float t = __expf(2.0f*x); return (t - 1.0f) * frcp(t + 1.0f); }
__device__ __forceinline__ float lrelu(float v){ return v > 0.0f ? v : 0.1f*v; }

// Per-wave LDS slab (floats), SLAB = 2560 -> 40960 B/block = 4 blocks/CU.
//  [0,800)    sXE : xe flat (l*16+c). After conv: sY aliases [400,700).
//  [800,1800) R1  : gi rows [50][20] -> sAT [50][16] -> sC [50][16]
//  [1800,2104) sX4 : x4 flat (l*6+h)
//  [2104,2504) sX4P: x4 padded [50][8]
//  [2504,2560) sFE : feat[54]
constexpr int SLAB = 2560;

__global__ __launch_bounds__(256, 4) void fused_kernel(
    const float* __restrict__ x,
    const float* __restrict__ we_w, const float* __restrict__ we_b,
    const float* __restrict__ attn_w, const float* __restrict__ attn_b,
    const float* __restrict__ c1w, const float* __restrict__ c1b,
    const float* __restrict__ c2w, const float* __restrict__ c2b,
    const float* __restrict__ c3w, const float* __restrict__ c3b,
    const float* __restrict__ wih, const float* __restrict__ whh,
    const float* __restrict__ bih, const float* __restrict__ bhh,
    const float* __restrict__ fc3w, const float* __restrict__ fc3b,
    float* __restrict__ out)
{
  __shared__ __align__(16) float smem[4 * SLAB];
  const int tid  = threadIdx.x;
  const int wave = tid >> 6;
  const int lane = tid & 63;
  const int b    = blockIdx.x * 4 + wave;

  float* S    = smem + wave * SLAB;
  float* sXE  = S;
  float* sY   = S + 400;
  float* R1   = S + 800;
  float* sX4  = S + 1800;
  float* sX4P = S + 2104;
  float* sFE  = S + 2504;

  const float* xb = x + (size_t)b * (LSEQ * DIN);

  // ---- Phase 1+3: lane l computes xe[l][0..15] and gi[l][0..17] ----
  if (lane < LSEQ) {
    float xv[DIN];
    const float4* xr = (const float4*)(xb + lane * DIN);
    #pragma unroll
    for (int q = 0; q < 5; ++q) {
      float4 v = xr[q];
      xv[4*q] = v.x; xv[4*q+1] = v.y; xv[4*q+2] = v.z; xv[4*q+3] = v.w;
    }
    float xe[CHN];
    #pragma unroll
    for (int c = 0; c < CHN; ++c) {
      float a = we_b[c];
      #pragma unroll
      for (int d = 0; d < DIN; ++d) a = fmaf(xv[d], we_w[c * DIN + d], a);
      xe[c] = a;
    }
    float4* xd = (float4*)(sXE + lane * CHN);
    xd[0] = make_float4(xe[0], xe[1], xe[2], xe[3]);
    xd[1] = make_float4(xe[4], xe[5], xe[6], xe[7]);
    xd[2] = make_float4(xe[8], xe[9], xe[10], xe[11]);
    xd[3] = make_float4(xe[12], xe[13], xe[14], xe[15]);
    float gi[18];
    #pragma unroll
    for (int g = 0; g < 18; ++g) {
      float a = bih[g];
      #pragma unroll
      for (int cc = 0; cc < CHN; ++cc) a = fmaf(xe[cc], wih[g * CHN + cc], a);
      gi[g] = a;
    }
    float4* gd = (float4*)(R1 + lane * 20);
    gd[0] = make_float4(gi[0], gi[1], gi[2], gi[3]);
    gd[1] = make_float4(gi[4], gi[5], gi[6], gi[7]);
    gd[2] = make_float4(gi[8], gi[9], gi[10], gi[11]);
    gd[3] = make_float4(gi[12], gi[13], gi[14], gi[15]);
    *(float2*)(R1 + lane * 20 + 16) = make_float2(gi[16], gi[17]);
  }
  __syncthreads();

  // ---- Phase 4: GRU — wave 0 runs all 4 elements, 16 lanes each ----
  // lanes: q = lane>>4 (element in block), g = lane&15 (gate 0..15).
  // Lanes g<2 also run gates 16+g as a second chain.
  if (wave == 0) {
    const int q = lane >> 4;
    const int g = lane & 15;
    const int gb = 16 + (g & 1);          // second-chain gate index (valid for g<2)
    float wa[HID], wb[HID];
    #pragma unroll
    for (int k = 0; k < HID; ++k) { wa[k] = whh[g * HID + k]; wb[k] = whh[gb * HID + k]; }
    const float ba = bhh[g];
    const float bb = bhh[gb];

    float* giq  = smem + q * SLAB + 800;    // gi rows [l][20]
    float* x4q  = smem + q * SLAB + 1800;
    float* x4pq = smem + q * SLAB + 2104;

    const int base   = q << 4;
    const int srcZ   = base + 6 + g;                       // z_g source lane
    const int srcN   = base + ((g < 4) ? (12 + g) : (g - 4)); // ghx/gix source lane

    float hh[HID];
    #pragma unroll
    for (int k = 0; k < HID; ++k) hh[k] = 0.0f;

    for (int l = 0; l < LSEQ; ++l) {
      const float gia = giq[l * 20 + g];          // gi[l][g]
      const float gib = giq[l * 20 + gb];         // gi[l][16+(g&1)]
      float gha = ba, ghb = bb;
      #pragma unroll
      for (int k = 0; k < HID; ++k) {
        gha = fmaf(wa[k], hh[k], gha);
        ghb = fmaf(wb[k], hh[k], ghb);
      }
      const float siga = fsig(gia + gha);         // valid r (g<6), z (6<=g<12)
      const float ghx = (g >= 12) ? gha : ghb;    // gate 12..15 on lanes 12-15; 16,17 on lanes 0,1
      const float gix = (g >= 12) ? gia : gib;
      const float ghn = __shfl(ghx, srcN);        // gh[12+g] for this lane's n
      const float gin = __shfl(gix, srcN);        // gi[12+g]
      const float z   = __shfl(siga, srcZ);       // z_g
      const float n   = ftanh(fmaf(siga, ghn, gin));  // r_g = siga (own lane, g<6)
      const float hn  = fmaf(z, hh[g < HID ? g : 0] - n, n);
      if (g < HID) {
        x4q[l * HID + g] = hn;
        x4pq[l * 8 + g]  = hn;
      }
      #pragma unroll
      for (int k = 0; k < HID; ++k) hh[k] = __shfl(hn, base + k);
    }
  }
  __syncthreads();

  // ---- Phase 2: attn rows (over dead gi) ----
  if (lane < LSEQ) {
    float a[CHN];
    #pragma unroll
    for (int cc = 0; cc < CHN; ++cc) a[cc] = sXE[cc * LSEQ + lane];
    float o[CHN];
    #pragma unroll
    for (int c = 0; c < CHN; ++c) {
      float acc = attn_b[c];
      #pragma unroll
      for (int cc = 0; cc < CHN; ++cc) acc = fmaf(a[cc], attn_w[c * CHN + cc], acc);
      o[c] = ftanh(acc);
    }
    float4* ad = (float4*)(R1 + lane * CHN);
    ad[0] = make_float4(o[0], o[1], o[2], o[3]);
    ad[1] = make_float4(o[4], o[5], o[6], o[7]);
    ad[2] = make_float4(o[8], o[9], o[10], o[11]);
    ad[3] = make_float4(o[12], o[13], o[14], o[15]);
  }
  __syncthreads();

  // ---- Phase 5: convs fused with attn1 reduction -> x_cnn[48] ----
  {
    float* sAT = R1;
    const int o = lane & 15;
    const int seg = lane >> 4;
    const int L0 = (seg < 2) ? seg * 13 : 26 + (seg - 2) * 12;
    const int NL = (seg < 2) ? 13 : 12;
    int mcl[17];
    #pragma unroll
    for (int mm = 0; mm < 17; ++mm) {
      int m = L0 - 2 + mm;
      mcl[mm] = min(max(m, 0), LSEQ - 1);
    }
    float z1[13], z2[13], z3[13];
    #pragma unroll
    for (int u = 0; u < 13; ++u) { z1[u] = 0.0f; z2[u] = 0.0f; z3[u] = 0.0f; }
    for (int i = 0; i < CHN; ++i) {
      const float w1 = c1w[o * CHN + i];
      float w2a[3], w3a[5];
      #pragma unroll
      for (int t = 0; t < 3; ++t) w2a[t] = c2w[(o * CHN + i) * 3 + t];
      #pragma unroll
      for (int t = 0; t < 5; ++t) w3a[t] = c3w[(o * CHN + i) * 5 + t];
      const float* xrow = sXE + i * LSEQ;
      float xv[17];
      #pragma unroll
      for (int mm = 0; mm < 17; ++mm) {
        float v = xrow[mcl[mm]];
        if (mm < 2 || mm >= 14) {
          int m = L0 - 2 + mm;
          v = (m == mcl[mm]) ? v : 0.0f;
        }
        xv[mm] = v;
      }
      #pragma unroll
      for (int u = 0; u < 13; ++u) {
        z1[u] = fmaf(w1, xv[u + 2], z1[u]);
        z2[u] = fmaf(w2a[0], xv[u + 1], z2[u]);
        z2[u] = fmaf(w2a[1], xv[u + 2], z2[u]);
        z2[u] = fmaf(w2a[2], xv[u + 3], z2[u]);
        z3[u] = fmaf(w3a[0], xv[u],     z3[u]);
        z3[u] = fmaf(w3a[1], xv[u + 1], z3[u]);
        z3[u] = fmaf(w3a[2], xv[u + 2], z3[u]);
        z3[u] = fmaf(w3a[3], xv[u + 3], z3[u]);
        z3[u] = fmaf(w3a[4], xv[u + 4], z3[u]);
      }
    }
    const float b1v = c1b[o], b2v = c2b[o], b3v = c3b[o];
    float a1 = 0.0f, a2 = 0.0f, a3 = 0.0f;
    #pragma unroll
    for (int u = 0; u < 13; ++u) {
      if (u < NL) {
        int l = L0 + u;
        float v1 = lrelu(z1[u] + b1v);
        float v2 = lrelu(z2[u] + b2v);
        float v3 = lrelu(z3[u] + b3v);
        int f1 = o * LSEQ + l;
        int f2 = (CHN + o) * LSEQ + l;
        int f3 = (2 * CHN + o) * LSEQ + l;
        a1 += v1 * sAT[(f1 / 48) * CHN + ((f1 % 48) & 15)];
        a2 += v2 * sAT[(f2 / 48) * CHN + ((f2 % 48) & 15)];
        a3 += v3 * sAT[(f3 / 48) * CHN + ((f3 % 48) & 15)];
      }
    }
    a1 += __shfl_xor(a1, 16); a1 += __shfl_xor(a1, 32);
    a2 += __shfl_xor(a2, 16); a2 += __shfl_xor(a2, 32);
    a3 += __shfl_xor(a3, 16); a3 += __shfl_xor(a3, 32);
    if (lane < CHN) { sFE[o] = a1; sFE[CHN + o] = a2; sFE[2 * CHN + o] = a3; }
  }
  __syncthreads();

  // ---- Phase 6a: T rows + column normalizers; sC[j] = {T[0..5], -, WX[8..13]} ----
  float* sC = R1;
  if (lane < LSEQ) {
    float colj[HID];
    #pragma unroll
    for (int h = 0; h < HID; ++h) colj[h] = sX4[h * LSEQ + lane];
    *(float4*)(sC + lane * 16)     = make_float4(colj[0], colj[1], colj[2], colj[3]);
    *(float2*)(sC + lane * 16 + 4) = make_float2(colj[4], colj[5]);
    float zs = 0.0f;
    for (int i = 0; i < LSEQ; ++i) {
      const float4 r0 = *(const float4*)(sX4P + i * 8);
      const float2 r1 = *(const float2*)(sX4P + i * 8 + 4);
      float s = r0.x * colj[0];
      s = fmaf(r0.y, colj[1], s); s = fmaf(r0.z, colj[2], s);
      s = fmaf(r0.w, colj[3], s); s = fmaf(r1.x, colj[4], s);
      s = fmaf(r1.y, colj[5], s);
      zs += __expf(s * (1.0f / 6.0f));
    }
    const float zi = frcp(zs);
    const float4 q0 = *(const float4*)(sX4P + lane * 8);
    const float2 q1 = *(const float2*)(sX4P + lane * 8 + 4);
    *(float4*)(sC + lane * 16 + 8)  = make_float4(zi*q0.x, zi*q0.y, zi*q0.z, zi*q0.w);
    *(float2*)(sC + lane * 16 + 12) = make_float2(zi*q1.x, zi*q1.y);
  }
  __syncthreads();

  // ---- Phase 6b: y0[i][h] = sum_j exp(s[i,j]/6) * WX[j][h] ----
  if (lane < LSEQ) {
    float rowi[HID];
    {
      const float4 q0 = *(const float4*)(sX4P + lane * 8);
      const float2 q1 = *(const float2*)(sX4P + lane * 8 + 4);
      rowi[0] = q0.x; rowi[1] = q0.y; rowi[2] = q0.z;
      rowi[3] = q0.w; rowi[4] = q1.x; rowi[5] = q1.y;
    }
    float ya[HID];
    #pragma unroll
    for (int h = 0; h < HID; ++h) ya[h] = 0.0f;
    for (int j = 0; j < LSEQ; ++j) {
      const float4 t0 = *(const float4*)(sC + j * 16);
      const float2 t1 = *(const float2*)(sC + j * 16 + 4);
      float s = rowi[0] * t0.x;
      s = fmaf(rowi[1], t0.y, s); s = fmaf(rowi[2], t0.z, s);
      s = fmaf(rowi[3], t0.w, s); s = fmaf(rowi[4], t1.x, s);
      s = fmaf(rowi[5], t1.y, s);
      const float e = __expf(s * (1.0f / 6.0f));
      const float4 w0 = *(const float4*)(sC + j * 16 + 8);
      const float2 w1 = *(const float2*)(sC + j * 16 + 12);
      ya[0] = fmaf(e, w0.x, ya[0]);
      ya[1] = fmaf(e, w0.y, ya[1]);
      ya[2] = fmaf(e, w0.z, ya[2]);
      ya[3] = fmaf(e, w0.w, ya[3]);
      ya[4] = fmaf(e, w1.x, ya[4]);
      ya[5] = fmaf(e, w1.y, ya[5]);
    }
    *(float2*)(sY + lane * 6)     = make_float2(ya[0], ya[1]);
    *(float2*)(sY + lane * 6 + 2) = make_float2(ya[2], ya[3]);
    *(float2*)(sY + lane * 6 + 4) = make_float2(ya[4], ya[5]);
  }
  __syncthreads();

  // ---- Phase 7: x_gru ----
  if (lane < HID) {
    float s = 0.0f;
    for (int m = 0; m < LSEQ; ++m) s += sY[lane * LSEQ + m];
    sFE[48 + lane] = s;
  }
  __syncthreads();

  // ---- Phase 8: fc ----
  if (lane < 2) {
    float acc = fc3b[lane];
    const float* wr = fc3w + lane * 54;
    #pragma unroll
    for (int k = 0; k < 54; ++k) acc = fmaf(wr[k], sFE[k], acc);
    out[(size_t)b * 2 + lane] = acc;
  }
}

extern "C" void kernel_launch(void* const* d_in, const int* in_sizes, int n_in,
                              void* d_out, int out_size, void* d_ws, size_t ws_size,
                              hipStream_t stream) {
  (void)in_sizes; (void)n_in; (void)d_ws; (void)ws_size; (void)out_size;
  fused_kernel<<<BATCH / 4, 256, 0, stream>>>(
      (const float*)d_in[0],
      (const float*)d_in[1],  (const float*)d_in[2],
      (const float*)d_in[3],  (const float*)d_in[4],
      (const float*)d_in[5],  (const float*)d_in[6],
      (const float*)d_in[7],  (const float*)d_in[8],
      (const float*)d_in[9],  (const float*)d_in[10],
      (const float*)d_in[11], (const float*)d_in[12],
      (const float*)d_in[13], (const float*)d_in[14],
      (const float*)d_in[15], (const float*)d_in[16],
      (float*)d_out);
}

// Round 7
// 294.454 us; speedup vs baseline: 1.2148x; 1.0001x over previous
//
#include <hip/hip_runtime.h>

#define BATCH 16384
#define LSEQ  50
#define DIN   20
#define CHN   16
#define HID   6

__device__ __forceinline__ float frcp(float x){ return __builtin_amdgcn_rcpf(x); }
__device__ __forceinline__ float fsig(float x){ return frcp(1.0f + __expf(-x)); }
__device__ __forceinline__ float ftanh(float x){ float t = __expf(2.0f*x); return (t - 1.0f) * frcp(t + 1.0f); }
__device__ __forceinline__ float lrelu(float v){ return v > 0.0f ? v : 0.1f*v; }

// Per-wave LDS slab (floats), SLAB = 2544 -> 40704 B/block = 4 blocks/CU.
//  [0,840)     sXEp: padded reshape/conv rows, stride 52: P[i][2+m] = xe_flat[i*50+m].
//              Row pads shared: row i's right pad == row i+1's left pad (both zero).
//              After conv: sY aliases [0,300).
//  [840,1840)  R1  : gi rows [50][20] -> sAT [50][16] -> sC [50][16]
//              sFE = R1+800 -> [1640,1696) (over dead gi tail; disjoint from sAT/sC)
//  [1840,2140) sX4 : x4 flat (l*6+h)
//  [2144,2544) sX4P: x4 padded [50][8] (16B-aligned rows)
constexpr int SLAB = 2544;

__global__ __launch_bounds__(256, 4) void fused_kernel(
    const float* __restrict__ x,
    const float* __restrict__ we_w, const float* __restrict__ we_b,
    const float* __restrict__ attn_w, const float* __restrict__ attn_b,
    const float* __restrict__ c1w, const float* __restrict__ c1b,
    const float* __restrict__ c2w, const float* __restrict__ c2b,
    const float* __restrict__ c3w, const float* __restrict__ c3b,
    const float* __restrict__ wih, const float* __restrict__ whh,
    const float* __restrict__ bih, const float* __restrict__ bhh,
    const float* __restrict__ fc3w, const float* __restrict__ fc3b,
    float* __restrict__ out)
{
  __shared__ __align__(16) float smem[4 * SLAB];
  const int tid  = threadIdx.x;
  const int wave = tid >> 6;
  const int lane = tid & 63;
  const int b    = blockIdx.x * 4 + wave;

  float* S    = smem + wave * SLAB;
  float* sXEp = S;
  float* sY   = S;          // alias, live after conv
  float* R1   = S + 840;
  float* sFE  = S + 1640;   // R1+800
  float* sX4  = S + 1840;
  float* sX4P = S + 2144;

  const float* xb = x + (size_t)b * (LSEQ * DIN);

  // ---- zero the shared row pads ----
  if (lane < CHN) {
    sXEp[lane * 52]     = 0.0f;
    sXEp[lane * 52 + 1] = 0.0f;
  } else if (lane == 16) {
    sXEp[832] = 0.0f;   // row 15 tail
    sXEp[833] = 0.0f;
  }

  // ---- Phase 1+3: lane l computes xe[l][0..15] (scatter to padded rows) and gi[l][0..17] ----
  if (lane < LSEQ) {
    float xv[DIN];
    const float4* xr = (const float4*)(xb + lane * DIN);
    #pragma unroll
    for (int q = 0; q < 5; ++q) {
      float4 v = xr[q];
      xv[4*q] = v.x; xv[4*q+1] = v.y; xv[4*q+2] = v.z; xv[4*q+3] = v.w;
    }
    float xe[CHN];
    #pragma unroll
    for (int c = 0; c < CHN; ++c) {
      float a = we_b[c];
      #pragma unroll
      for (int d = 0; d < DIN; ++d) a = fmaf(xv[d], we_w[c * DIN + d], a);
      xe[c] = a;
    }
    // scatter: kk = 16*lane + c ; i = kk/50, m = kk%50 ; addr = 52i + 2 + m
    const int kk0 = lane * CHN;
    const int i0  = kk0 / 50;
    const int m0  = kk0 - i0 * 50;
    float* basep = sXEp + i0 * 52 + 2 + m0;
    #pragma unroll
    for (int c = 0; c < CHN; ++c) {
      const int off = c + ((m0 + c >= 50) ? 2 : 0);   // row wrap skips the 2-float pad
      basep[off] = xe[c];
    }
    float gi[18];
    #pragma unroll
    for (int g = 0; g < 18; ++g) {
      float a = bih[g];
      #pragma unroll
      for (int cc = 0; cc < CHN; ++cc) a = fmaf(xe[cc], wih[g * CHN + cc], a);
      gi[g] = a;
    }
    float4* gd = (float4*)(R1 + lane * 20);
    gd[0] = make_float4(gi[0], gi[1], gi[2], gi[3]);
    gd[1] = make_float4(gi[4], gi[5], gi[6], gi[7]);
    gd[2] = make_float4(gi[8], gi[9], gi[10], gi[11]);
    gd[3] = make_float4(gi[12], gi[13], gi[14], gi[15]);
    *(float2*)(R1 + lane * 20 + 16) = make_float2(gi[16], gi[17]);
  }
  __syncthreads();

  // ---- Phase 4: GRU — wave 0 runs all 4 elements, 16 lanes each ----
  if (wave == 0) {
    const int q = lane >> 4;
    const int g = lane & 15;
    const int gb = 16 + (g & 1);
    float wa[HID], wb[HID];
    #pragma unroll
    for (int k = 0; k < HID; ++k) { wa[k] = whh[g * HID + k]; wb[k] = whh[gb * HID + k]; }
    const float ba = bhh[g];
    const float bb = bhh[gb];

    float* giq  = smem + q * SLAB + 840;
    float* x4q  = smem + q * SLAB + 1840;
    float* x4pq = smem + q * SLAB + 2144;

    const int base = q << 4;
    const int srcZ = base + 6 + g;
    const int srcN = base + ((g < 4) ? (12 + g) : (g - 4));

    float hh[HID];
    #pragma unroll
    for (int k = 0; k < HID; ++k) hh[k] = 0.0f;

    for (int l = 0; l < LSEQ; ++l) {
      const float gia = giq[l * 20 + g];
      const float gib = giq[l * 20 + gb];
      float gha = ba, ghb = bb;
      #pragma unroll
      for (int k = 0; k < HID; ++k) {
        gha = fmaf(wa[k], hh[k], gha);
        ghb = fmaf(wb[k], hh[k], ghb);
      }
      const float siga = fsig(gia + gha);
      const float ghx = (g >= 12) ? gha : ghb;
      const float gix = (g >= 12) ? gia : gib;
      const float ghn = __shfl(ghx, srcN);
      const float gin = __shfl(gix, srcN);
      const float z   = __shfl(siga, srcZ);
      const float n   = ftanh(fmaf(siga, ghn, gin));
      const float hn  = fmaf(z, hh[g < HID ? g : 0] - n, n);
      if (g < HID) {
        x4q[l * HID + g] = hn;
        x4pq[l * 8 + g]  = hn;
      }
      #pragma unroll
      for (int k = 0; k < HID; ++k) hh[k] = __shfl(hn, base + k);
    }
  }
  __syncthreads();

  // ---- Phase 2: attn rows (write sAT over dead gi) ----
  if (lane < LSEQ) {
    float a[CHN];
    #pragma unroll
    for (int cc = 0; cc < CHN; ++cc) a[cc] = sXEp[cc * 52 + 2 + lane];  // reshape view
    float o[CHN];
    #pragma unroll
    for (int c = 0; c < CHN; ++c) {
      float acc = attn_b[c];
      #pragma unroll
      for (int cc = 0; cc < CHN; ++cc) acc = fmaf(a[cc], attn_w[c * CHN + cc], acc);
      o[c] = ftanh(acc);
    }
    float4* ad = (float4*)(R1 + lane * CHN);
    ad[0] = make_float4(o[0], o[1], o[2], o[3]);
    ad[1] = make_float4(o[4], o[5], o[6], o[7]);
    ad[2] = make_float4(o[8], o[9], o[10], o[11]);
    ad[3] = make_float4(o[12], o[13], o[14], o[15]);
  }
  __syncthreads();

  // ---- Phase 5: convs (vector LDS loads, padded rows) fused with attn1 reduction ----
  {
    float* sAT = R1;
    const int o   = lane & 15;
    const int seg = lane >> 4;
    const int s   = seg * 12;               // 0,12,24,36 -> 16B-aligned within 52-stride rows
    const int NL  = (seg == 3) ? 14 : 12;
    float z1[14], z2[14], z3[14];
    #pragma unroll
    for (int u = 0; u < 14; ++u) { z1[u] = 0.0f; z2[u] = 0.0f; z3[u] = 0.0f; }
    for (int i = 0; i < CHN; ++i) {
      const float w1 = c1w[o * CHN + i];
      float w2a[3], w3a[5];
      #pragma unroll
      for (int t = 0; t < 3; ++t) w2a[t] = c2w[(o * CHN + i) * 3 + t];
      #pragma unroll
      for (int t = 0; t < 5; ++t) w3a[t] = c3w[(o * CHN + i) * 5 + t];
      const float4* wp = (const float4*)(sXEp + i * 52 + s);
      float4 q0 = wp[0], q1 = wp[1], q2 = wp[2], q3 = wp[3], q4 = wp[4];
      float xv[20] = {q0.x,q0.y,q0.z,q0.w, q1.x,q1.y,q1.z,q1.w,
                      q2.x,q2.y,q2.z,q2.w, q3.x,q3.y,q3.z,q3.w,
                      q4.x,q4.y,q4.z,q4.w};
      // output l = s+u uses padded positions [s+u, s+u+4] = xv[u..u+4]
      #pragma unroll
      for (int u = 0; u < 14; ++u) {
        z1[u] = fmaf(w1, xv[u + 2], z1[u]);
        z2[u] = fmaf(w2a[0], xv[u + 1], z2[u]);
        z2[u] = fmaf(w2a[1], xv[u + 2], z2[u]);
        z2[u] = fmaf(w2a[2], xv[u + 3], z2[u]);
        z3[u] = fmaf(w3a[0], xv[u],     z3[u]);
        z3[u] = fmaf(w3a[1], xv[u + 1], z3[u]);
        z3[u] = fmaf(w3a[2], xv[u + 2], z3[u]);
        z3[u] = fmaf(w3a[3], xv[u + 3], z3[u]);
        z3[u] = fmaf(w3a[4], xv[u + 4], z3[u]);
      }
    }
    const float b1v = c1b[o], b2v = c2b[o], b3v = c3b[o];
    float a1 = 0.0f, a2 = 0.0f, a3 = 0.0f;
    #pragma unroll
    for (int u = 0; u < 14; ++u) {
      if (u < NL) {
        int l = s + u;
        float v1 = lrelu(z1[u] + b1v);
        float v2 = lrelu(z2[u] + b2v);
        float v3 = lrelu(z3[u] + b3v);
        int f1 = o * LSEQ + l;
        int f2 = (CHN + o) * LSEQ + l;
        int f3 = (2 * CHN + o) * LSEQ + l;
        a1 += v1 * sAT[(f1 / 48) * CHN + ((f1 % 48) & 15)];
        a2 += v2 * sAT[(f2 / 48) * CHN + ((f2 % 48) & 15)];
        a3 += v3 * sAT[(f3 / 48) * CHN + ((f3 % 48) & 15)];
      }
    }
    a1 += __shfl_xor(a1, 16); a1 += __shfl_xor(a1, 32);
    a2 += __shfl_xor(a2, 16); a2 += __shfl_xor(a2, 32);
    a3 += __shfl_xor(a3, 16); a3 += __shfl_xor(a3, 32);
    if (lane < CHN) { sFE[o] = a1; sFE[CHN + o] = a2; sFE[2 * CHN + o] = a3; }
  }
  __syncthreads();

  // ---- Phase 6a: T rows + column normalizers; sC[j] = {T[0..5], -, WX[8..13]} ----
  float* sC = R1;
  if (lane < LSEQ) {
    float colj[HID];
    #pragma unroll
    for (int h = 0; h < HID; ++h) colj[h] = sX4[h * LSEQ + lane];   // reshape view
    *(float4*)(sC + lane * 16)     = make_float4(colj[0], colj[1], colj[2], colj[3]);
    *(float2*)(sC + lane * 16 + 4) = make_float2(colj[4], colj[5]);
    float zs = 0.0f;
    for (int i = 0; i < LSEQ; ++i) {
      const float4 r0 = *(const float4*)(sX4P + i * 8);
      const float2 r1 = *(const float2*)(sX4P + i * 8 + 4);
      float s = r0.x * colj[0];
      s = fmaf(r0.y, colj[1], s); s = fmaf(r0.z, colj[2], s);
      s = fmaf(r0.w, colj[3], s); s = fmaf(r1.x, colj[4], s);
      s = fmaf(r1.y, colj[5], s);
      zs += __expf(s * (1.0f / 6.0f));
    }
    const float zi = frcp(zs);
    const float4 q0 = *(const float4*)(sX4P + lane * 8);
    const float2 q1 = *(const float2*)(sX4P + lane * 8 + 4);
    *(float4*)(sC + lane * 16 + 8)  = make_float4(zi*q0.x, zi*q0.y, zi*q0.z, zi*q0.w);
    *(float2*)(sC + lane * 16 + 12) = make_float2(zi*q1.x, zi*q1.y);
  }
  __syncthreads();

  // ---- Phase 6b: y0[i][h] = sum_j exp(s[i,j]/6) * WX[j][h] ----
  if (lane < LSEQ) {
    float rowi[HID];
    {
      const float4 q0 = *(const float4*)(sX4P + lane * 8);
      const float2 q1 = *(const float2*)(sX4P + lane * 8 + 4);
      rowi[0] = q0.x; rowi[1] = q0.y; rowi[2] = q0.z;
      rowi[3] = q0.w; rowi[4] = q1.x; rowi[5] = q1.y;
    }
    float ya[HID];
    #pragma unroll
    for (int h = 0; h < HID; ++h) ya[h] = 0.0f;
    for (int j = 0; j < LSEQ; ++j) {
      const float4 t0 = *(const float4*)(sC + j * 16);
      const float2 t1 = *(const float2*)(sC + j * 16 + 4);
      float s = rowi[0] * t0.x;
      s = fmaf(rowi[1], t0.y, s); s = fmaf(rowi[2], t0.z, s);
      s = fmaf(rowi[3], t0.w, s); s = fmaf(rowi[4], t1.x, s);
      s = fmaf(rowi[5], t1.y, s);
      const float e = __expf(s * (1.0f / 6.0f));
      const float4 w0 = *(const float4*)(sC + j * 16 + 8);
      const float2 w1 = *(const float2*)(sC + j * 16 + 12);
      ya[0] = fmaf(e, w0.x, ya[0]);
      ya[1] = fmaf(e, w0.y, ya[1]);
      ya[2] = fmaf(e, w0.z, ya[2]);
      ya[3] = fmaf(e, w0.w, ya[3]);
      ya[4] = fmaf(e, w1.x, ya[4]);
      ya[5] = fmaf(e, w1.y, ya[5]);
    }
    *(float2*)(sY + lane * 6)     = make_float2(ya[0], ya[1]);
    *(float2*)(sY + lane * 6 + 2) = make_float2(ya[2], ya[3]);
    *(float2*)(sY + lane * 6 + 4) = make_float2(ya[4], ya[5]);
  }
  __syncthreads();

  // ---- Phase 7: x_gru ----
  if (lane < HID) {
    float s = 0.0f;
    for (int m = 0; m < LSEQ; ++m) s += sY[lane * LSEQ + m];
    sFE[48 + lane] = s;
  }
  __syncthreads();

  // ---- Phase 8: fc ----
  if (lane < 2) {
    float acc = fc3b[lane];
    const float* wr = fc3w + lane * 54;
    #pragma unroll
    for (int k = 0; k < 54; ++k) acc = fmaf(wr[k], sFE[k], acc);
    out[(size_t)b * 2 + lane] = acc;
  }
}

extern "C" void kernel_launch(void* const* d_in, const int* in_sizes, int n_in,
                              void* d_out, int out_size, void* d_ws, size_t ws_size,
                              hipStream_t stream) {
  (void)in_sizes; (void)n_in; (void)d_ws; (void)ws_size; (void)out_size;
  fused_kernel<<<BATCH / 4, 256, 0, stream>>>(
      (const float*)d_in[0],
      (const float*)d_in[1],  (const float*)d_in[2],
      (const float*)d_in[3],  (const float*)d_in[4],
      (const float*)d_in[5],  (const float*)d_in[6],
      (const float*)d_in[7],  (const float*)d_in[8],
      (const float*)d_in[9],  (const float*)d_in[10],
      (const float*)d_in[11], (const float*)d_in[12],
      (const float*)d_in[13], (const float*)d_in[14],
      (const float*)d_in[15], (const float*)d_in[16],
      (float*)d_out);
}